// Round 5
// baseline (494.696 us; speedup 1.0000x reference)
//
#include <hip/hip_runtime.h>
#include <math.h>

// ExpertPool: B=2,N=1024 -> T=2048 tokens, D=768, E=8, H=3072, top-K=2
#define T_TOK 2048
#define DIM   768
#define NEXP  8
#define HDIM  3072
#define MAXP  (T_TOK * 2)   // exactly 4096 (token,expert) pairs
#define BSTR  776           // B LDS row stride in ushorts (+8 pad: conflict-free frag reads)

typedef __attribute__((ext_vector_type(8))) short bfrag;   // 8 bf16 (4 VGPRs)
typedef __attribute__((ext_vector_type(4))) float f32x4;   // MFMA C/D

__device__ __forceinline__ unsigned short f2bf(float f) {
  union { float f; unsigned int u; } x; x.f = f;
  unsigned int r = x.u + 0x7fffu + ((x.u >> 16) & 1u);  // RNE
  return (unsigned short)(r >> 16);
}

// async 16B global->LDS; LDS dest = wave-uniform base + lane*16 (contiguous).
__device__ __forceinline__ void async16(const void* g, void* l) {
  __builtin_amdgcn_global_load_lds(
      (const __attribute__((address_space(1))) void*)g,
      (__attribute__((address_space(3))) void*)l, 16, 0, 0);
}

// ---------------- routing: per-expert contiguous row lists ----------------
__global__ void k_route(const float* __restrict__ disp,
                        const float* __restrict__ comb,
                        int* __restrict__ meta,        // [0..7]=cnt, [8..15]=off
                        float* __restrict__ row_comb,
                        int* __restrict__ row_token,
                        int* __restrict__ tok2pair) {  // (T_TOK,2)
  __shared__ int s_cnt[NEXP], s_off[NEXP], s_cur[NEXP];
  __shared__ int s_tn[T_TOK];
  int tid = threadIdx.x;                               // 1024 threads
  if (tid < NEXP) s_cnt[tid] = 0;
  for (int t = tid; t < T_TOK; t += 1024) s_tn[t] = 0;
  __syncthreads();
  for (int t = tid; t < T_TOK; t += 1024)
    for (int e = 0; e < NEXP; ++e)
      if (disp[t * NEXP + e] > 0.f) atomicAdd(&s_cnt[e], 1);
  __syncthreads();
  if (tid == 0) {
    int acc = 0;
    for (int e = 0; e < NEXP; ++e) { s_off[e] = acc; acc += s_cnt[e]; }
  }
  __syncthreads();
  if (tid < NEXP) {
    s_cur[tid] = s_off[tid];
    meta[tid] = s_cnt[tid];
    meta[NEXP + tid] = s_off[tid];
  }
  __syncthreads();
  for (int t = tid; t < T_TOK; t += 1024)
    for (int e = 0; e < NEXP; ++e)
      if (disp[t * NEXP + e] > 0.f) {
        int p = atomicAdd(&s_cur[e], 1);
        row_token[p] = t;
        row_comb[p] = comb[t * NEXP + e];
        int sl = atomicAdd(&s_tn[t], 1);
        tok2pair[t * 2 + sl] = p;
      }
}

// ---------------- X -> bf16 once (3 MB) ----------------
__global__ void k_xcvt(const float* __restrict__ X, unsigned short* __restrict__ Xb) {
  size_t i = ((size_t)blockIdx.x * 256 + threadIdx.x) * 8;
  float4 a = *(const float4*)(X + i);
  float4 b = *(const float4*)(X + i + 4);
  unsigned short r[8];
  r[0]=f2bf(a.x); r[1]=f2bf(a.y); r[2]=f2bf(a.z); r[3]=f2bf(a.w);
  r[4]=f2bf(b.x); r[5]=f2bf(b.y); r[6]=f2bf(b.z); r[7]=f2bf(b.w);
  *(uint4*)(Xb + i) = *(uint4*)r;
}

// ======= GEMM 1, weight-stationary: u = gelu(X@Wg^T)*(X@Wv^T) -> bf16 =======
// Block = (e, 32-wide n-slab). Full K=768 of Wg,Wv staged once in LDS (fp32->bf16
// in-register, read from HBM exactly once). Loop all M-tiles of the expert.
// BK=128, XOR-swizzled async A staging (conflict-free ds_read_b128).
__global__ __launch_bounds__(256, 1) void k_gvB(
    const unsigned short* __restrict__ Xb,   // (T_TOK, DIM) bf16
    const float* __restrict__ Wg,            // (NEXP, HDIM, DIM)
    const float* __restrict__ Wv,
    const int* __restrict__ meta,
    const int* __restrict__ row_token,
    unsigned short* __restrict__ ubuf)       // (MAXP, HDIM) bf16
{
  int nt = blockIdx.x;            // 0..95
  int e  = blockIdx.y;
  int n0 = nt * 32;
  int cnt = meta[e], off = meta[NEXP + e];
  if (cnt <= 0) return;

  __shared__ unsigned short Bg[32 * BSTR];   // 48.5 KB
  __shared__ unsigned short Bv[32 * BSTR];   // 48.5 KB
  __shared__ unsigned short As[128 * 128];   // 32 KB: 128 rows x 16 chunks x 8 bf16

  int tid = threadIdx.x;
  int wid = tid >> 6, lane = tid & 63;
  int wm = (wid >> 1) * 64;        // {0,64}
  int wn = (wid & 1) * 16;         // {0,16}
  int lr = lane & 15, quad = lane >> 4;

  // ---- stage both weight slabs: 32 rows x 768 K, fp32 -> bf16 ----
  const float* WgB = Wg + ((size_t)e * HDIM + n0) * DIM;
  const float* WvB = Wv + ((size_t)e * HDIM + n0) * DIM;
  for (int c = tid; c < 32 * 192; c += 256) {
    int row = c / 192, k4 = c % 192;
    float4 g = *(const float4*)(WgB + (size_t)row * DIM + k4 * 4);
    ushort4 gp; gp.x=f2bf(g.x); gp.y=f2bf(g.y); gp.z=f2bf(g.z); gp.w=f2bf(g.w);
    *(ushort4*)(&Bg[row * BSTR + k4 * 4]) = gp;
    float4 v = *(const float4*)(WvB + (size_t)row * DIM + k4 * 4);
    ushort4 vp; vp.x=f2bf(v.x); vp.y=f2bf(v.y); vp.z=f2bf(v.z); vp.w=f2bf(v.w);
    *(ushort4*)(&Bv[row * BSTR + k4 * 4]) = vp;
  }

  // swizzled A-source chunk offset for this thread (elements)
  int koff = (((tid & 15) ^ (tid >> 4)) * 8);
  int mt_n = (cnt + 127) >> 7;

  for (int mt = 0; mt < mt_n; ++mt) {
    int m0 = mt << 7;
    int tok[8];
#pragma unroll
    for (int r = 0; r < 8; ++r) {
      int row = (tid >> 4) + 16 * r;
      int gr = m0 + row; if (gr >= cnt) gr = cnt - 1;
      tok[r] = row_token[off + gr];
    }
    f32x4 zero4 = {0.f, 0.f, 0.f, 0.f};
    f32x4 accg[4], accv[4];
#pragma unroll
    for (int i = 0; i < 4; ++i) { accg[i] = zero4; accv[i] = zero4; }

    for (int k0 = 0; k0 < DIM; k0 += 128) {
      __syncthreads();
#pragma unroll
      for (int r = 0; r < 8; ++r)
        async16(Xb + (size_t)tok[r] * DIM + k0 + koff, &As[(tid + 256 * r) * 8]);
      __syncthreads();
#pragma unroll
      for (int h = 0; h < 4; ++h) {
        bfrag bg = *(const bfrag*)(&Bg[(wn + lr) * BSTR + k0 + h * 32 + quad * 8]);
        bfrag bv = *(const bfrag*)(&Bv[(wn + lr) * BSTR + k0 + h * 32 + quad * 8]);
        int kc = (h * 4 + quad);
#pragma unroll
        for (int i = 0; i < 4; ++i) {
          int m = wm + i * 16 + lr;
          bfrag a = *(const bfrag*)(&As[m * 128 + (kc ^ lr) * 8]);
          accg[i] = __builtin_amdgcn_mfma_f32_16x16x32_bf16(a, bg, accg[i], 0, 0, 0);
          accv[i] = __builtin_amdgcn_mfma_f32_16x16x32_bf16(a, bv, accv[i], 0, 0, 0);
        }
      }
    }

    // epilogue: gelu_exact(g)*v, one bf16 round, store
#pragma unroll
    for (int i = 0; i < 4; ++i)
#pragma unroll
      for (int rg = 0; rg < 4; ++rg) {
        int gr = m0 + wm + i * 16 + quad * 4 + rg;
        if (gr < cnt) {
          float g = accg[i][rg];
          float v = accv[i][rg];
          float u = 0.5f * g * (1.0f + erff(g * 0.70710678118654752f)) * v;
          ubuf[(size_t)(off + gr) * HDIM + n0 + wn + lr] = f2bf(u);
        }
      }
  }
}

// ======= GEMM 2, weight-stationary: u @ Wo^T -> w-scaled partials (split-K x4) =======
__global__ __launch_bounds__(256, 1) void k_outB(
    const unsigned short* __restrict__ U,    // (MAXP, HDIM) bf16
    const float* __restrict__ Wo,            // (NEXP, DIM, HDIM)
    const float* __restrict__ scale,
    const int* __restrict__ meta,
    const float* __restrict__ row_comb,
    float* __restrict__ partial)             // (4, MAXP, DIM)
{
  int x = blockIdx.x;              // 0..47
  int nt = x >> 2, ks = x & 3;
  int e  = blockIdx.y;
  int n0 = nt * 64;                // DIM cols
  int kb = ks * 768;               // HDIM quarter
  int cnt = meta[e], off = meta[NEXP + e];
  if (cnt <= 0) return;

  __shared__ unsigned short Bs[64 * BSTR];   // 97 KB
  __shared__ unsigned short As[128 * 128];   // 32 KB

  int tid = threadIdx.x;
  int wid = tid >> 6, lane = tid & 63;
  int wm = (wid >> 1) * 64;        // {0,64}
  int wn = (wid & 1) * 32;         // {0,32}
  int lr = lane & 15, quad = lane >> 4;

  // ---- stage Wo slab: 64 rows x 768 K (quarter), fp32 -> bf16 ----
  const float* WoB = Wo + ((size_t)e * DIM + n0) * HDIM + kb;
  for (int c = tid; c < 64 * 192; c += 256) {
    int row = c / 192, k4 = c % 192;
    float4 b = *(const float4*)(WoB + (size_t)row * HDIM + k4 * 4);
    ushort4 bp; bp.x=f2bf(b.x); bp.y=f2bf(b.y); bp.z=f2bf(b.z); bp.w=f2bf(b.w);
    *(ushort4*)(&Bs[row * BSTR + k4 * 4]) = bp;
  }

  int koff = (((tid & 15) ^ (tid >> 4)) * 8);
  int mt_n = (cnt + 127) >> 7;
  float sc = scale[e];

  for (int mt = 0; mt < mt_n; ++mt) {
    int m0 = mt << 7;
    int arow[8];
#pragma unroll
    for (int r = 0; r < 8; ++r) {
      int row = (tid >> 4) + 16 * r;
      int gr = m0 + row; if (gr >= cnt) gr = cnt - 1;
      arow[r] = off + gr;
    }
    f32x4 zero4 = {0.f, 0.f, 0.f, 0.f};
    f32x4 acc[4][2];
#pragma unroll
    for (int i = 0; i < 4; ++i) { acc[i][0] = zero4; acc[i][1] = zero4; }

    for (int k0 = 0; k0 < 768; k0 += 128) {
      __syncthreads();
#pragma unroll
      for (int r = 0; r < 8; ++r)
        async16(U + (size_t)arow[r] * HDIM + kb + k0 + koff, &As[(tid + 256 * r) * 8]);
      __syncthreads();
#pragma unroll
      for (int h = 0; h < 4; ++h) {
        bfrag b0 = *(const bfrag*)(&Bs[(wn + lr) * BSTR + k0 + h * 32 + quad * 8]);
        bfrag b1 = *(const bfrag*)(&Bs[(wn + 16 + lr) * BSTR + k0 + h * 32 + quad * 8]);
        int kc = (h * 4 + quad);
#pragma unroll
        for (int i = 0; i < 4; ++i) {
          int m = wm + i * 16 + lr;
          bfrag a = *(const bfrag*)(&As[m * 128 + (kc ^ lr) * 8]);
          acc[i][0] = __builtin_amdgcn_mfma_f32_16x16x32_bf16(a, b0, acc[i][0], 0, 0, 0);
          acc[i][1] = __builtin_amdgcn_mfma_f32_16x16x32_bf16(a, b1, acc[i][1], 0, 0, 0);
        }
      }
    }

#pragma unroll
    for (int i = 0; i < 4; ++i)
#pragma unroll
      for (int rg = 0; rg < 4; ++rg) {
        int gr = m0 + wm + i * 16 + quad * 4 + rg;
        if (gr < cnt) {
          int p = off + gr;
          float w = row_comb[p] * sc;
          float* pb = partial + ((size_t)ks * MAXP + p) * DIM + n0;
          pb[wn + lr]      = acc[i][0][rg] * w;
          pb[wn + 16 + lr] = acc[i][1][rg] * w;
        }
      }
  }
}

// ---------------- combine: out[t] = sum over 2 pairs x 4 K-splits ----------------
__global__ void k_combine(const float* __restrict__ partial,
                          const int* __restrict__ tok2pair,
                          float* __restrict__ out) {
  int idx = blockIdx.x * 256 + threadIdx.x;   // T_TOK * 192
  int t = idx / 192, d4 = idx % 192;
  int p0 = tok2pair[t * 2], p1 = tok2pair[t * 2 + 1];
  float sx = 0.f, sy = 0.f, sz = 0.f, sw = 0.f;
#pragma unroll
  for (int ks = 0; ks < 4; ++ks) {
    float4 a = *(const float4*)(partial + ((size_t)ks * MAXP + p0) * DIM + d4 * 4);
    float4 b = *(const float4*)(partial + ((size_t)ks * MAXP + p1) * DIM + d4 * 4);
    sx += a.x + b.x; sy += a.y + b.y; sz += a.z + b.z; sw += a.w + b.w;
  }
  float4 r; r.x = sx; r.y = sy; r.z = sz; r.w = sw;
  *(float4*)(out + (size_t)t * DIM + d4 * 4) = r;
}

extern "C" void kernel_launch(void* const* d_in, const int* in_sizes, int n_in,
                              void* d_out, int out_size, void* d_ws, size_t ws_size,
                              hipStream_t stream) {
  const float* tokens = (const float*)d_in[0];
  const float* disp   = (const float*)d_in[1];
  const float* comb   = (const float*)d_in[2];
  const float* Wg     = (const float*)d_in[3];
  const float* Wv     = (const float*)d_in[4];
  const float* Wo     = (const float*)d_in[5];
  const float* scale  = (const float*)d_in[6];
  float* out = (float*)d_out;

  const size_t MB = 1ull << 20;
  char* ws = (char*)d_ws;
  int*   meta      = (int*)ws;
  int*   row_token = (int*)(ws + 16384);
  float* row_comb  = (float*)(ws + 32768);
  int*   tok2pair  = (int*)(ws + 49152);
  unsigned short* Xb   = (unsigned short*)(ws + 1 * MB);   // 3 MB
  unsigned short* ubuf = (unsigned short*)(ws + 4 * MB);   // 24 MB
  float* partial       = (float*)(ws + 28 * MB);           // 48 MB

  hipLaunchKernelGGL(k_route, dim3(1), dim3(1024), 0, stream,
                     disp, comb, meta, row_comb, row_token, tok2pair);
  hipLaunchKernelGGL(k_xcvt, dim3((T_TOK * DIM) / (256 * 8)), dim3(256), 0, stream,
                     tokens, Xb);
  hipLaunchKernelGGL(k_gvB, dim3(HDIM / 32, NEXP), dim3(256), 0, stream,
                     Xb, Wg, Wv, meta, row_token, ubuf);
  hipLaunchKernelGGL(k_outB, dim3((DIM / 64) * 4, NEXP), dim3(256), 0, stream,
                     ubuf, Wo, scale, meta, row_comb, partial);
  hipLaunchKernelGGL(k_combine, dim3((T_TOK * DIM / 4) / 256), dim3(256), 0, stream,
                     partial, tok2pair, out);
}